// Round 13
// baseline (809.233 us; speedup 1.0000x reference)
//
#include <hip/hip_runtime.h>

typedef unsigned short u16;
typedef unsigned int   u32;
typedef _Float16       f16;
typedef __attribute__((ext_vector_type(8))) _Float16 f16x8;
typedef __attribute__((ext_vector_type(4))) float    f32x4;
typedef __attribute__((ext_vector_type(4))) double   dbl4;

#define NSLOT_ 16384   // N * K = 8192 * 2

__device__ __forceinline__ u16 f16bits(f16 h){ union{f16 f; u16 u;} x; x.f = h; return x.u; }

__device__ __forceinline__ void gl_lds16(const void* gptr, void* lptr){
  __builtin_amdgcn_global_load_lds((const __attribute__((address_space(1))) u32*)gptr,
                                   (__attribute__((address_space(3))) u32*)lptr, 16, 0, 0);
}

// swizzled LDS offset (u16 units) for row-pair-interleaved layout, BK=32.
__device__ __forceinline__ int roff(int row, int lks){
  return ((row >> 1) << 6) + ((lks ^ ((row >> 1) & 3)) << 4) + ((row & 1) << 3);
}

// ---------------- per-token LayerNorm over D=512 (f64 math, f32 out) ----------------
__global__ __launch_bounds__(256) void ln_kernel(const float* __restrict__ x,
    const float* __restrict__ g, const float* __restrict__ bb, float* __restrict__ h){
  int n = blockIdx.x, t = threadIdx.x;
  const float* xr = x + ((size_t)n << 9);
  float2 v = *(const float2*)&xr[t*2];
  double vx = v.x, vy = v.y;
  double s = vx + vy;
  double q = vx*vx + vy*vy;
  #pragma unroll
  for (int o = 32; o > 0; o >>= 1){ s += __shfl_down(s, o, 64); q += __shfl_down(q, o, 64); }
  __shared__ double ls[4], lq_[4];
  __shared__ double sm, sv;
  int wid = t >> 6, lane = t & 63;
  if (lane == 0){ ls[wid] = s; lq_[wid] = q; }
  __syncthreads();
  if (t == 0){
    double S = ls[0]+ls[1]+ls[2]+ls[3], Q = lq_[0]+lq_[1]+lq_[2]+lq_[3];
    double mean = S * (1.0/512.0);
    double var  = Q * (1.0/512.0) - mean*mean;
    sm = mean; sv = 1.0/sqrt(var + 1e-5);
  }
  __syncthreads();
  double mean = sm, inv = sv;
  int d = t*2;
  float2 o;
  o.x = (float)((vx - mean)*inv*(double)g[d]   + (double)bb[d]);
  o.y = (float)((vy - mean)*inv*(double)g[d+1] + (double)bb[d+1]);
  *(float2*)&h[((size_t)n<<9) + d] = o;
}

// ---------------- fused gather(+residual) for layer l, then LN of layer l+1 ----------------
__global__ __launch_bounds__(128) void gather_ln(const float* __restrict__ xin,
    const float* __restrict__ eo, const int* __restrict__ slot_of, const float* __restrict__ wv,
    const float* __restrict__ g, const float* __restrict__ bb,
    float* __restrict__ out, float* __restrict__ h){
  int n = blockIdx.x, t = threadIdx.x;
  int s0 = slot_of[2*n], s1 = slot_of[2*n+1];
  double w0 = wv[2*n], w1 = wv[2*n+1];
  float4 xi = *(const float4*)&xin[((size_t)n << 9) + t*4];
  float4 e0 = *(const float4*)&eo[((size_t)s0 << 9) + t*4];
  float4 e1 = *(const float4*)&eo[((size_t)s1 << 9) + t*4];
  double o0 = (double)xi.x + w0*(double)e0.x + w1*(double)e1.x;
  double o1 = (double)xi.y + w0*(double)e0.y + w1*(double)e1.y;
  double o2 = (double)xi.z + w0*(double)e0.z + w1*(double)e1.z;
  double o3 = (double)xi.w + w0*(double)e0.w + w1*(double)e1.w;
  float4 o; o.x = (float)o0; o.y = (float)o1; o.z = (float)o2; o.w = (float)o3;
  *(float4*)&out[((size_t)n << 9) + t*4] = o;
  double vx = o.x, vy = o.y, vz = o.z, vw = o.w;
  double s = vx+vy+vz+vw;
  double q = vx*vx+vy*vy+vz*vz+vw*vw;
  #pragma unroll
  for (int off = 32; off > 0; off >>= 1){ s += __shfl_down(s, off, 64); q += __shfl_down(q, off, 64); }
  __shared__ double ls[2], lq_[2];
  __shared__ double sm, sv;
  int wid = t >> 6, lane = t & 63;
  if (lane == 0){ ls[wid] = s; lq_[wid] = q; }
  __syncthreads();
  if (t == 0){
    double S = ls[0]+ls[1], Q = lq_[0]+lq_[1];
    double mean = S * (1.0/512.0);
    double var  = Q * (1.0/512.0) - mean*mean;
    sm = mean; sv = 1.0/sqrt(var + 1e-5);
  }
  __syncthreads();
  double mean = sm, inv = sv;
  int d = t*4;
  float4 ho;
  ho.x = (float)((vx - mean)*inv*(double)g[d]   + (double)bb[d]);
  ho.y = (float)((vy - mean)*inv*(double)g[d+1] + (double)bb[d+1]);
  ho.z = (float)((vz - mean)*inv*(double)g[d+2] + (double)bb[d+2]);
  ho.w = (float)((vw - mean)*inv*(double)g[d+3] + (double)bb[d+3]);
  *(float4*)&h[((size_t)n<<9) + d] = ho;
}

// ---------------- column stats, stage 1: partials over 128-row T-chunks ----------------
// grid 512 = b(8) x colchunk(8) x tchunk(8)
__global__ __launch_bounds__(256) void colstats(const float* __restrict__ h,
    double* __restrict__ pS, double* __restrict__ pQ){
  int bid = blockIdx.x;
  int b  = bid >> 6;
  int ch = (bid >> 3) & 7;
  int tc = bid & 7;
  int t = threadIdx.x;
  int col = ch*64 + (t & 63);
  int tp = t >> 6;
  const float* base = h + ((size_t)b << 19) + ((size_t)(tc*128) << 9);
  double s = 0.0, q = 0.0;
  for (int tt = tp; tt < 128; tt += 4){
    double v = (double)base[((size_t)tt << 9) + col];
    s += v; q += v*v;
  }
  __shared__ double ls[4][64], lq[4][64];
  ls[tp][t & 63] = s; lq[tp][t & 63] = q;
  __syncthreads();
  if (tp == 0){
    double S = ls[0][t]+ls[1][t]+ls[2][t]+ls[3][t];
    double Q = lq[0][t]+lq[1][t]+lq[2][t]+lq[3][t];
    pS[((tc<<3)+b)*512 + col] = S;
    pQ[((tc<<3)+b)*512 + col] = Q;
  }
}

// ---------------- subject MLP -> per-(b,d) affine a,c (f64); reduces colstat partials ----------------
__global__ __launch_bounds__(256) void subj_kernel(const int* __restrict__ sid,
    const float* __restrict__ semb,
    const float* __restrict__ h1w, const float* __restrict__ h1b,
    const float* __restrict__ h2w, const float* __restrict__ h2b,
    const float* __restrict__ s1w, const float* __restrict__ s1b,
    const float* __restrict__ s2w, const float* __restrict__ s2b,
    const double* __restrict__ pS, const double* __restrict__ pQ,
    double* __restrict__ a64, double* __restrict__ c64, int l){
  __shared__ double ev[64], hid1[128], hh[128], sh[64], sp[1024];
  __shared__ double cs_s[512], cq_s[512];
  int t = threadIdx.x;
  int b = blockIdx.x;
  for (int d = t; d < 512; d += 256){
    double S = 0.0, Q = 0.0;
    #pragma unroll
    for (int tc = 0; tc < 8; ++tc){
      S += pS[((tc<<3)+b)*512 + d];
      Q += pQ[((tc<<3)+b)*512 + d];
    }
    cs_s[d] = S; cq_s[d] = Q;
  }
  int s = sid[b];
  if (t < 64) ev[t] = (double)semb[l*4096 + s*64 + t];
  __syncthreads();
  if (t < 128){
    double acc = (double)h1b[l*128 + t];
    for (int i = 0; i < 64; ++i) acc += ev[i]*(double)h1w[l*8192 + i*128 + t];
    hid1[t] = acc > 0.0 ? acc : 0.0;
  }
  __syncthreads();
  if (t < 128){
    double acc = (double)h2b[l*128 + t];
    for (int i = 0; i < 128; ++i) acc += hid1[i]*(double)h2w[l*16384 + i*128 + t];
    hh[t] = acc;
  }
  __syncthreads();
  if (t < 64){
    double acc = (double)s1b[l*64 + t];
    for (int i = 0; i < 128; ++i) acc += hh[i]*(double)s1w[l*8192 + i*64 + t];
    sh[t] = acc > 0.0 ? acc : 0.0;
  }
  __syncthreads();
  for (int m = t; m < 1024; m += 256){
    double acc = (double)s2b[l*1024 + m];
    for (int j = 0; j < 64; ++j) acc += sh[j]*(double)s2w[l*65536 + j*1024 + m];
    sp[m] = acc;
  }
  __syncthreads();
  for (int d = t; d < 512; d += 256){
    double mu  = cs_s[d] * (1.0/1024.0);
    double var = cq_s[d] * (1.0/1024.0) - mu*mu;
    double inv = 1.0/sqrt(var + 1e-8);
    double spv = sp[d];
    double gamma = (spv > 30.0 ? spv : log1p(exp(spv))) + 1e-8;
    double beta  = sp[512 + d];
    double A = gamma * inv;
    a64[(b<<9)+d] = A;
    c64[(b<<9)+d] = beta - mu*A;
  }
}

// ---------------- hf = h*a + c -> fp16 hi/lo' (lo scaled 2^11); block 0 zeros counts/cur ----------------
__global__ __launch_bounds__(256) void hfcast(const float* __restrict__ h,
    const double* __restrict__ a64, const double* __restrict__ c64,
    u16* __restrict__ hfh, u16* __restrict__ hfl, int* __restrict__ counts){
  if (blockIdx.x == 0 && threadIdx.x < 16) counts[threadIdx.x] = 0;
  size_t i0 = ((size_t)blockIdx.x*256 + threadIdx.x) * 8;
  int n = (int)(i0 >> 9);
  int d0 = (int)(i0 & 511);
  int b = n >> 10;
  float4 x0 = *(const float4*)&h[i0];
  float4 x1 = *(const float4*)&h[i0 + 4];
  dbl4 a0 = *(const dbl4*)&a64[(b<<9) + d0];
  dbl4 a1 = *(const dbl4*)&a64[(b<<9) + d0 + 4];
  dbl4 c0 = *(const dbl4*)&c64[(b<<9) + d0];
  dbl4 c1 = *(const dbl4*)&c64[(b<<9) + d0 + 4];
  float f[8];
  f[0] = (float)((double)x0.x*a0[0] + c0[0]);
  f[1] = (float)((double)x0.y*a0[1] + c0[1]);
  f[2] = (float)((double)x0.z*a0[2] + c0[2]);
  f[3] = (float)((double)x0.w*a0[3] + c0[3]);
  f[4] = (float)((double)x1.x*a1[0] + c1[0]);
  f[5] = (float)((double)x1.y*a1[1] + c1[1]);
  f[6] = (float)((double)x1.z*a1[2] + c1[2]);
  f[7] = (float)((double)x1.w*a1[3] + c1[3]);
  ushort4 oh0, oh1, ol0, ol1;
  u16 vh[8], vl[8];
  #pragma unroll
  for (int j = 0; j < 8; ++j){
    f16 hi = (f16)f[j];
    float rem = (f[j] - (float)hi) * 2048.f;
    f16 lo = (f16)rem;
    vh[j] = f16bits(hi); vl[j] = f16bits(lo);
  }
  oh0.x=vh[0]; oh0.y=vh[1]; oh0.z=vh[2]; oh0.w=vh[3];
  oh1.x=vh[4]; oh1.y=vh[5]; oh1.z=vh[6]; oh1.w=vh[7];
  ol0.x=vl[0]; ol0.y=vl[1]; ol0.z=vl[2]; ol0.w=vl[3];
  ol1.x=vl[4]; ol1.y=vl[5]; ol1.z=vl[6]; ol1.w=vl[7];
  *(ushort4*)&hfh[i0]   = oh0;
  *(ushort4*)&hfh[i0+4] = oh1;
  *(ushort4*)&hfl[i0]   = ol0;
  *(ushort4*)&hfl[i0+4] = ol1;
}

// ---------------- gating: fp16-split MFMA (f32 accum) + f64 finish (split-k g2), top-2 ----------------
__global__ __launch_bounds__(256) void gate2_kernel(const u16* __restrict__ hfh,
    const u16* __restrict__ hfl, const u16* __restrict__ g1Th, const u16* __restrict__ g1Tl,
    const float* __restrict__ g1b, const float* __restrict__ g2w, const float* __restrict__ g2b,
    int* __restrict__ idxo, float* __restrict__ wo_, int* __restrict__ counts){
  __shared__ double hid_s[16][258];
  __shared__ double lg[16*8];
  __shared__ double lg2[256];
  __shared__ int lcnt[8];
  int t = threadIdx.x, w = t >> 6, l = t & 63;
  int tok0 = blockIdx.x << 4;
  if (t < 8) lcnt[t] = 0;
  int lr = l & 15, lks = l >> 4;
  const u16* ahp = hfh + ((size_t)(tok0 + lr) << 9) + lks*8;
  const u16* alp = hfl + ((size_t)(tok0 + lr) << 9) + lks*8;
  const u16* bhp[4]; const u16* blp[4];
  #pragma unroll
  for (int nf = 0; nf < 4; ++nf){
    int col = w*64 + nf*16 + lr;
    bhp[nf] = g1Th + ((size_t)col << 9) + lks*8;
    blp[nf] = g1Tl + ((size_t)col << 9) + lks*8;
  }
  f32x4 hh[4], cr[4];
  #pragma unroll
  for (int nf = 0; nf < 4; ++nf)
    #pragma unroll
    for (int r = 0; r < 4; ++r){ hh[nf][r] = 0.f; cr[nf][r] = 0.f; }
  f16x8 ah = *(const f16x8*)ahp;
  f16x8 al = *(const f16x8*)alp;
  for (int kc = 0; kc < 512; kc += 32){
    int kn = (kc + 32) & 511;
    f16x8 ahn = *(const f16x8*)(ahp + kn);
    f16x8 aln = *(const f16x8*)(alp + kn);
    #pragma unroll
    for (int nf = 0; nf < 4; ++nf){
      f16x8 bh = *(const f16x8*)(bhp[nf] + kc);
      f16x8 bl = *(const f16x8*)(blp[nf] + kc);
      hh[nf] = __builtin_amdgcn_mfma_f32_16x16x32_f16(ah, bh, hh[nf], 0, 0, 0);
      cr[nf] = __builtin_amdgcn_mfma_f32_16x16x32_f16(ah, bl, cr[nf], 0, 0, 0);
      cr[nf] = __builtin_amdgcn_mfma_f32_16x16x32_f16(al, bh, cr[nf], 0, 0, 0);
    }
    ah = ahn; al = aln;
  }
  #pragma unroll
  for (int nf = 0; nf < 4; ++nf){
    int col = w*64 + nf*16 + lr;
    double gb = (double)g1b[col];
    #pragma unroll
    for (int r = 0; r < 4; ++r){
      int row = lks*4 + r;
      double v = (double)hh[nf][r] + (double)cr[nf][r]*(1.0/2048.0) + gb;
      hid_s[row][col] = v > 0.0 ? v : 0.0;
    }
  }
  __syncthreads();
  {
    int pair = t >> 1, kh = t & 1;
    int tok = pair >> 3, e = pair & 7;
    double la = kh ? 0.0 : (double)g2b[e];
    int k0 = kh << 7;
    for (int k = k0; k < k0 + 128; ++k) la += hid_s[tok][k]*(double)g2w[(k<<3)+e];
    lg2[t] = la;
  }
  __syncthreads();
  if (t < 128) lg[t] = lg2[2*t] + lg2[2*t+1];
  __syncthreads();
  if (t < 16){
    double l0[8];
    #pragma unroll
    for (int e = 0; e < 8; ++e) l0[e] = lg[(t<<3)+e];
    double m = l0[0];
    #pragma unroll
    for (int e = 1; e < 8; ++e) m = fmax(m, l0[e]);
    double p[8]; double s = 0.0;
    #pragma unroll
    for (int e = 0; e < 8; ++e){ p[e] = exp(l0[e]-m); s += p[e]; }
    double b1 = -1e300, b2 = -1e300; int i1 = 0, i2 = 1;
    #pragma unroll
    for (int e = 0; e < 8; ++e){
      double v = l0[e];
      if (v > b1){ b2 = b1; i2 = i1; b1 = v; i1 = e; }
      else if (v > b2){ b2 = v; i2 = e; }
    }
    double pr1 = p[i1]/s, pr2 = p[i2]/s;
    double den = pr1 + pr2 + 1e-8;
    int n = tok0 + t;
    idxo[2*n] = i1; idxo[2*n+1] = i2;
    wo_[2*n] = (float)(pr1/den); wo_[2*n+1] = (float)(pr2/den);
    atomicAdd(&lcnt[i1], 1); atomicAdd(&lcnt[i2], 1);
  }
  __syncthreads();
  if (t < 8) atomicAdd(&counts[t], lcnt[t]);
}

// ---------------- scatter (computes offs locally from final counts; block 0 publishes) ----------------
__global__ __launch_bounds__(256) void scatter_kernel(const int* __restrict__ idx,
    const int* __restrict__ counts, int* __restrict__ cur,
    int* __restrict__ offs, int* __restrict__ tok_of, int* __restrict__ slot_of){
  __shared__ int lcnt[8], lbase[8], offs_s[8];
  int t = threadIdx.x;
  int n = blockIdx.x*256 + t;
  if (t < 8) lcnt[t] = 0;
  if (t == 0){
    int run = 0;
    for (int e = 0; e < 8; ++e){ offs_s[e] = run; run += counts[e]; }
  }
  __syncthreads();
  if (blockIdx.x == 0 && t < 8) offs[t] = offs_s[t];
  int e0 = idx[2*n], e1 = idx[2*n+1];
  int p0 = atomicAdd(&lcnt[e0], 1);
  int p1 = atomicAdd(&lcnt[e1], 1);
  __syncthreads();
  if (t < 8) lbase[t] = atomicAdd(&cur[t], lcnt[t]);
  __syncthreads();
  int s0 = offs_s[e0] + lbase[e0] + p0;
  int s1 = offs_s[e1] + lbase[e1] + p1;
  tok_of[s0] = n; tok_of[s1] = n;
  slot_of[2*n] = s0; slot_of[2*n+1] = s1;
}

// ---------------- merged weight transpose + fp16 hi/lo' split (all 4 weights, 1 launch) ----------------
__device__ __forceinline__ void cvt_tile(const float* __restrict__ src,
    u16* __restrict__ dh, u16* __restrict__ dl, int R, int C, int bx){
  int tilesC = C >> 5, tilesR = R >> 5;
  int e = bx / (tilesR*tilesC);
  int rem = bx % (tilesR*tilesC);
  int rt = rem / tilesC, ct = rem % tilesC;
  __shared__ float tile[32][33];
  int t = threadIdx.x;
  int j = t & 31, i0 = t >> 5;
  const float* s = src + (size_t)e*R*C + (size_t)(rt*32)*C + ct*32;
  for (int ii = i0; ii < 32; ii += 8) tile[ii][j] = s[(size_t)ii*C + j];
  __syncthreads();
  size_t ob = (size_t)e*R*C + (size_t)(ct*32)*R + rt*32;
  for (int ii = i0; ii < 32; ii += 8){
    float v = tile[j][ii];
    f16 hi = (f16)v;
    float rem2 = (v - (float)hi) * 2048.f;
    f16 lo = (f16)rem2;
    dh[ob + (size_t)ii*R + j] = f16bits(hi);
    dl[ob + (size_t)ii*R + j] = f16bits(lo);
  }
}

__global__ __launch_bounds__(256) void cvt_all(const float* __restrict__ wi0,
    const float* __restrict__ wi1, const float* __restrict__ wo, const float* __restrict__ g1w,
    u16* __restrict__ w0Th, u16* __restrict__ w0Tl, u16* __restrict__ w1Th, u16* __restrict__ w1Tl,
    u16* __restrict__ woTh, u16* __restrict__ woTl, u16* __restrict__ g1Th, u16* __restrict__ g1Tl){
  int bx = blockIdx.x;
  if (bx < 4096)       cvt_tile(wi0, w0Th, w0Tl, 512, 1024, bx);
  else if (bx < 8192)  cvt_tile(wi1, w1Th, w1Tl, 512, 1024, bx - 4096);
  else if (bx < 12288) cvt_tile(wo,  woTh, woTl, 1024, 512, bx - 8192);
  else                 cvt_tile(g1w, g1Th, g1Tl, 512, 256,  bx - 12288);
}

// ---------------- layer-1 up-GEMM: fp16-split, 128r x 64c, all-LDS swizzled (r12) ----------------
// grid: e(8) x mt(128) x nt(16)
__global__ __launch_bounds__(256) void up1_kernel(const u16* __restrict__ hfh,
    const u16* __restrict__ hfl,
    const u16* __restrict__ w0h, const u16* __restrict__ w0l,
    const u16* __restrict__ w1h, const u16* __restrict__ w1l,
    const int* __restrict__ tok_of, const int* __restrict__ offs, const int* __restrict__ counts,
    u16* __restrict__ hidh, u16* __restrict__ hidl){
  int bx = blockIdx.x;
  int e  = bx >> 11;
  int mt = (bx >> 4) & 127;
  int nt = bx & 15;
  int base = offs[e], cnt = counts[e];
  int row0 = mt << 7;
  if (row0 >= cnt) return;
  __shared__ __align__(16) u16 Ah[2][4096], Alo[2][4096];
  __shared__ __align__(16) u16 B0h[2][2048], B0l[2][2048], B1h[2][2048], B1l[2][2048];
  int t = threadIdx.x, w = t >> 6, l = t & 63;
  int wm = w >> 1, wn = w & 1;
  int lr = l & 15, lks = l >> 4;
  int riw = ((l >> 3) << 1) | (l & 1);
  int kc16s = ((((l >> 1) & 3) ^ ((l >> 3) & 3)) << 3);
  int ar1 = w*16 + riw;
  int tokA1, tokA2;
  { int ss = base + row0 + ar1;      ss = ss < NSLOT_ ? ss : NSLOT_-1; tokA1 = tok_of[ss]; }
  { int ss = base + row0 + 64 + ar1; ss = ss < NSLOT_ ? ss : NSLOT_-1; tokA2 = tok_of[ss]; }
  const u16* sAh1 = hfh + ((size_t)tokA1 << 9) + kc16s;
  const u16* sAh2 = hfh + ((size_t)tokA2 << 9) + kc16s;
  const u16* sAl1 = hfl + ((size_t)tokA1 << 9) + kc16s;
  const u16* sAl2 = hfl + ((size_t)tokA2 << 9) + kc16s;
  size_t bcol = (size_t)(e*1024 + nt*64);
  size_t bci = (bcol + (size_t)ar1) << 9;
  const u16* sB0h = w0h + bci + kc16s;
  const u16* sB0l = w0l + bci + kc16s;
  const u16* sB1h = w1h + bci + kc16s;
  const u16* sB1l = w1l + bci + kc16s;
  int aoff[4], boff[2];
  #pragma unroll
  for (int mi = 0; mi < 4; ++mi) aoff[mi] = roff(wm*64 + mi*16 + lr, lks);
  #pragma unroll
  for (int ni = 0; ni < 2; ++ni) boff[ni] = roff(wn*32 + ni*16 + lr, lks);
  f32x4 hh0[4][2], cr0[4][2], hh1[4][2], cr1[4][2];
  #pragma unroll
  for (int i = 0; i < 4; ++i)
    #pragma unroll
    for (int j = 0; j < 2; ++j)
      #pragma unroll
      for (int r = 0; r < 4; ++r){ hh0[i][j][r]=0.f; cr0[i][j][r]=0.f; hh1[i][j][r]=0.f; cr1[i][j][r]=0.f; }
#define STG_U(buf, kc) do{ \
    gl_lds16(sAh1 + (kc), &Ah[buf][t*8]); \
    gl_lds16(sAh2 + (kc), &Ah[buf][2048 + t*8]); \
    gl_lds16(sAl1 + (kc), &Alo[buf][t*8]); \
    gl_lds16(sAl2 + (kc), &Alo[buf][2048 + t*8]); \
    gl_lds16(sB0h + (kc), &B0h[buf][t*8]); \
    gl_lds16(sB0l + (kc), &B0l[buf][t*8]); \
    gl_lds16(sB1h + (kc), &B1h[buf][t*8]); \
    gl_lds16(sB1l + (kc), &B1l[buf][t*8]); }while(0)
  STG_U(0, 0);
  for (int ks = 0; ks < 16; ++ks){
    int cur = ks & 1;
    __syncthreads();
    if (ks < 15) STG_U(cur^1, (ks+1)*32);
    f16x8 ah[4], al[4], b0hv[2], b0lv[2], b1hv[2], b1lv[2];
    #pragma unroll
    for (int mi = 0; mi < 4; ++mi){
      ah[mi] = *(const f16x8*)&Ah[cur][aoff[mi]];
      al[mi] = *(const f16x8*)&Alo[cur][aoff[mi]];
    }
    #pragma unroll
    for (int ni = 0; ni < 2; ++ni){
      b0hv[ni] = *(const f16x8*)&B0h[cur][boff[ni]];
      b0lv[ni] = *(const f16x8*)&B0l[cur][boff[ni]];
      b1hv[ni] = *(const f16x8*)&B1h[cur][boff[ni]];
      b1lv[ni] = *(const f16x8*)&B1l[cur][boff[ni]];
    }
    #pragma unroll
    for (int mi = 0; mi < 4; ++mi)
      #pragma unroll
      for (int ni = 0; ni < 2; ++ni){
        hh0[mi][ni] = __builtin_amdgcn_mfma_f32_16x16x32_f16(ah[mi], b0hv[ni], hh0[mi][ni], 0, 0, 0);
        hh1[mi][ni] = __builtin_amdgcn_mfma_f32_16x16x32_f16(ah[mi], b1hv[ni], hh1[mi][ni], 0, 0, 0);
        cr0[mi][ni] = __builtin_amdgcn_mfma_f32_16x16x32_f16(ah[mi], b0lv[ni], cr0[mi][ni], 0, 0, 0);
        cr0[mi][ni] = __builtin_amdgcn_mfma_f32_16x16x32_f16(al[mi], b0hv[ni], cr0[mi][ni], 0, 0, 0);
        cr1[mi][ni] = __builtin_amdgcn_mfma_f32_16x16x32_f16(ah[mi], b1lv[ni], cr1[mi][ni], 0, 0, 0);
        cr1[mi][ni] = __builtin_amdgcn_mfma_f32_16x16x32_f16(al[mi], b1hv[ni], cr1[mi][ni], 0, 0, 0);
      }
  }
#undef STG_U
  #pragma unroll
  for (int mi = 0; mi < 4; ++mi){
    int rb = row0 + wm*64 + mi*16 + lks*4;
    #pragma unroll
    for (int r = 0; r < 4; ++r){
      int rr = rb + r;
      if (rr < cnt){
        size_t orow = ((size_t)(base + rr) << 10) + nt*64;
        #pragma unroll
        for (int ni = 0; ni < 2; ++ni){
          int col = wn*32 + ni*16 + lr;
          float u0 = hh0[mi][ni][r] + cr0[mi][ni][r]*(1.f/2048.f);
          float u1 = hh1[mi][ni][r] + cr1[mi][ni][r]*(1.f/2048.f);
          u0 = u0 > 0.f ? u0 : 0.f;
          float v = u0*u1;
          f16 vh = (f16)v;
          float rem = (v - (float)vh)*2048.f;
          hidh[orow + col] = f16bits(vh);
          hidl[orow + col] = f16bits((f16)rem);
        }
      }
    }
  }
}

// ---------------- layer-1 down-GEMM: fp16-split, 128r x 128c; waves 2x2 (r7-proven) ----------------
// grid: e(8) x mt(128) x nt(4)
__global__ __launch_bounds__(256) void down1_kernel(const u16* __restrict__ hidh,
    const u16* __restrict__ hidl, const u16* __restrict__ wdh, const u16* __restrict__ wdl,
    const int* __restrict__ offs, const int* __restrict__ counts, float* __restrict__ eo){
  int bx = blockIdx.x;
  int e  = bx >> 9;
  int mt = (bx >> 2) & 127;
  int nt = bx & 3;
  int base = offs[e], cnt = counts[e];
  int row0 = mt << 7;
  if (row0 >= cnt) return;
  __shared__ __align__(16) u16 Ah[2][4096], Alo[2][4096];
  __shared__ __align__(16) u16 Bh[2][4096], Bl[2][4096];
  int t = threadIdx.x, w = t >> 6, l = t & 63;
  int wm = w >> 1, wn = w & 1;
  int lr = l & 15, lks = l >> 4;
  int riw = ((l >> 3) << 1) | (l & 1);
  int kc16s = ((((l >> 1) & 3) ^ ((l >> 3) & 3)) << 3);
  int ar1 = w*16 + riw;
  int sA1c = base + row0 + ar1;      sA1c = sA1c < NSLOT_ ? sA1c : NSLOT_-1;
  int sA2c = base + row0 + 64 + ar1; sA2c = sA2c < NSLOT_ ? sA2c : NSLOT_-1;
  const u16* sAh1 = hidh + ((size_t)sA1c << 10) + kc16s;
  const u16* sAh2 = hidh + ((size_t)sA2c << 10) + kc16s;
  const u16* sAl1 = hidl + ((size_t)sA1c << 10) + kc16s;
  const u16* sAl2 = hidl + ((size_t)sA2c << 10) + kc16s;
  size_t bcol = (size_t)(e*512 + nt*128);
  const u16* sBh1 = wdh + ((bcol + (size_t)ar1) << 10) + kc16s;
  const u16* sBh2 = wdh + ((bcol + 64 + (size_t)ar1) << 10) + kc16s;
  const u16* sBl1 = wdl + ((bcol + (size_t)ar1) << 10) + kc16s;
  const u16* sBl2 = wdl + ((bcol + 64 + (size_t)ar1) << 10) + kc16s;
  int aoff[4], boff[4];
  #pragma unroll
  for (int mi = 0; mi < 4; ++mi) aoff[mi] = roff(wm*64 + mi*16 + lr, lks);
  #pragma unroll
  for (int ni = 0; ni < 4; ++ni) boff[ni] = roff(wn*64 + ni*16 + lr, lks);
  f32x4 hh[4][4], cr[4][4];
  #pragma unroll
  for (int i = 0; i < 4; ++i)
    #pragma unroll
    for (int j = 0; j < 4; ++j)
      #pragma unroll
      for (int r = 0; r < 4; ++r){ hh[i][j][r]=0.f; cr[i][j][r]=0.f; }
#define STG_D(buf, kc) do{ \
    gl_lds16(sAh1 + (kc), &Ah[buf][t*8]); \
    gl_lds16(sAh2 + (kc), &Ah[buf][2048 + t*8]); \
    gl_lds16(sAl1 + (kc), &Alo[buf][t*8]); \
    gl_lds16(sAl2 + (kc), &Alo[buf][2048 + t*8]); \
    gl_lds16(sBh1 + (kc), &Bh[buf][t*8]); \
    gl_lds16(sBh2 + (kc), &Bh[buf][2048 + t*8]); \
    gl_lds16(sBl1 + (kc), &Bl[buf][t*8]); \
    gl_lds16(sBl2 + (kc), &Bl[buf][2048 + t*8]); }while(0)
  STG_D(0, 0);
  for (int ks = 0; ks < 32; ++ks){
    int cur = ks & 1;
    __syncthreads();
    if (ks < 31) STG_D(cur^1, (ks+1)*32);
    f16x8 ah[4], al[4], bh[4], bl[4];
    #pragma unroll
    for (int mi = 0; mi < 4; ++mi){
      ah[mi] = *(const f16x8*)&Ah[cur][aoff[mi]];
      al[mi] = *(const f16x8*)&Alo[cur][aoff[mi]];
    }
    #pragma unroll
    for (int ni = 0; ni < 4; ++ni){
      bh[ni] = *(const f16x8*)&Bh[cur][boff[ni]];
      bl[ni] = *(const f16x8*)&Bl[cur][boff[ni]];
    }
    #pragma unroll
    for (int mi = 0; mi < 4; ++mi)
      #pragma unroll
      for (int ni = 0; ni < 4; ++ni){
        hh[mi][ni] = __builtin_amdgcn_mfma_f32_16x16x32_f16(ah[mi], bh[ni], hh[mi][ni], 0, 0, 0);
        cr[mi][ni] = __builtin_amdgcn_mfma_f32_16x16x32_f16(ah[mi], bl[ni], cr[mi][ni], 0, 0, 0);
        cr[mi][ni] = __builtin_amdgcn_mfma_f32_16x16x32_f16(al[mi], bh[ni], cr[mi][ni], 0, 0, 0);
      }
  }
#undef STG_D
  #pragma unroll
  for (int mi = 0; mi < 4; ++mi){
    int rb = row0 + wm*64 + mi*16 + lks*4;
    #pragma unroll
    for (int r = 0; r < 4; ++r){
      int rr = rb + r;
      if (rr < cnt){
        float* orow = eo + (((size_t)(base + rr)) << 9) + nt*128;
        #pragma unroll
        for (int ni = 0; ni < 4; ++ni)
          orow[wn*64 + ni*16 + lr] = hh[mi][ni][r] + cr[mi][ni][r]*(1.f/2048.f);
      }
    }
  }
}

// ---------------- layer-2 up-GEMM: fp16 hi-only, 128r x 128c; waves 2x2 (r12) ----------------
// grid: e(8) x mt(128) x nt(8)
__global__ __launch_bounds__(256) void uph_kernel(const u16* __restrict__ hfh,
    const u16* __restrict__ w0h, const u16* __restrict__ w1h,
    const int* __restrict__ tok_of, const int* __restrict__ offs, const int* __restrict__ counts,
    u16* __restrict__ hidh){
  int bx = blockIdx.x;
  int e  = bx >> 10;
  int mt = (bx >> 3) & 127;
  int nt = bx & 7;
  int base = offs[e], cnt = counts[e];
  int row0 = mt << 7;
  if (row0 >= cnt) return;
  __shared__ __align__(16) u16 Ah[2][4096];
  __shared__ __align__(16) u16 B0[2][4096], B1[2][4096];
  int t = threadIdx.x, w = t >> 6, l = t & 63;
  int wm = w >> 1, wn = w & 1;
  int lr = l & 15, lks = l >> 4;
  int riw = ((l >> 3) << 1) | (l & 1);
  int kc16s = ((((l >> 1) & 3) ^ ((l >> 3) & 3)) << 3);
  int ar1 = w*16 + riw;
  int tokA1, tokA2;
  { int ss = base + row0 + ar1;      ss = ss < NSLOT_ ? ss : NSLOT_-1; tokA1 = tok_of[ss]; }
  { int ss = base + row0 + 64 + ar1; ss = ss < NSLOT_ ? ss : NSLOT_-1; tokA2 = tok_of[ss]; }
  const u16* sAh1 = hfh + ((size_t)tokA1 << 9) + kc16s;
  const u16* sAh2 = hfh + ((size_t)tokA2 << 9) + kc16s;
  size_t bcol = (size_t)(e*1024 + nt*128);
  const u16* sB0a = w0h + ((bcol + (size_t)ar1) << 9) + kc16s;
  const u16* sB0b = w0h + ((bcol + 64 + (size_t)ar1) << 9) + kc16s;
  const u16* sB1a = w1h + ((bcol + (size_t)ar1) << 9) + kc16s;
  const u16* sB1b = w1h + ((bcol + 64 + (size_t)ar1) << 9) + kc16s;
  int aoff[4], boff[4];
  #pragma unroll
  for (int mi = 0; mi < 4; ++mi) aoff[mi] = roff(wm*64 + mi*16 + lr, lks);
  #pragma unroll
  for (int ni = 0; ni < 4; ++ni) boff[ni] = roff(wn*64 + ni*16 + lr, lks);
  f32x4 hh0[4][4], hh1[4][4];
  #pragma unroll
  for (int i = 0; i < 4; ++i)
    #pragma unroll
    for (int j = 0; j < 4; ++j)
      #pragma unroll
      for (int r = 0; r < 4; ++r){ hh0[i][j][r]=0.f; hh1[i][j][r]=0.f; }
#define STG_UH(buf, kc) do{ \
    gl_lds16(sAh1 + (kc), &Ah[buf][t*8]); \
    gl_lds16(sAh2 + (kc), &Ah[buf][2048 + t*8]); \
    gl_lds16(sB0a + (kc), &B0[buf][t*8]); \
    gl_lds16(sB0b + (kc), &B0[buf][2048 + t*8]); \
    gl_lds16(sB1a + (kc), &B1[buf][t*8]); \
    gl_lds16(sB1b + (kc), &B1[buf][2048 + t*8]); }while(0)
  STG_UH(0, 0);
  for (int ks = 0; ks < 16; ++ks){
    int cur = ks & 1;
    __syncthreads();
    if (ks < 15) STG_UH(cur^1, (ks+1)*32);
    f16x8 ah[4], b0v[4], b1v[4];
    #pragma unroll
    for (int mi = 0; mi < 4; ++mi) ah[mi] = *(const f16x8*)&Ah[cur][aoff[mi]];
    #pragma unroll
    for (int ni = 0; ni < 4; ++ni){
      b0v[ni] = *(const f16x8*)&B0[cur][boff[ni]];
      b1v[ni] = *(const f16x8*)&B1[cur][boff[ni]];
    }
    #pragma unroll
    for (int mi = 0; mi < 4; ++mi)
      #pragma unroll
      for (int ni = 0; ni < 4; ++ni){
        hh0[mi][ni] = __builtin_amdgcn_mfma_f32_16x16x32_f16(ah[mi], b0v[ni], hh0[mi][ni], 0, 0, 0);
        hh1[mi][ni] = __builtin_amdgcn_mfma_f32_16x16x32_f16(ah[mi], b1v[ni], hh1[mi][ni], 0, 0, 0);
      }
  }
#undef STG_UH
  #pragma unroll
  for (int mi = 0; mi < 4; ++mi){
    int rb = row0 + wm*64 + mi*16 + lks*4;
    #pragma unroll
    for (int r = 0; r < 4; ++r){
      int rr = rb + r;
      if (rr < cnt){
        size_t orow = ((size_t)(base + rr) << 10) + nt*128;
        #pragma unroll
        for (int ni = 0; ni < 4; ++ni){
          int col = wn*64 + ni*16 + lr;
          float u0 = hh0[mi][ni][r];
          u0 = u0 > 0.f ? u0 : 0.f;
          hidh[orow + col] = f16bits((f16)(u0*hh1[mi][ni][r]));
        }
      }
    }
  }
}

// ---------------- layer-2 down-GEMM: fp16 hi-only, 128r x 128c; waves 2x2 (r12) ----------------
// grid: e(8) x mt(128) x nt(4)
__global__ __launch_bounds__(256) void dnh_kernel(const u16* __restrict__ hidh,
    const u16* __restrict__ wdh,
    const int* __restrict__ offs, const int* __restrict__ counts, float* __restrict__ eo){
  int bx = blockIdx.x;
  int e  = bx >> 9;
  int mt = (bx >> 2) & 127;
  int nt = bx & 3;
  int base = offs[e], cnt = counts[e];
  int row0 = mt << 7;
  if (row0 >= cnt) return;
  __shared__ __align__(16) u16 Ah[2][4096];
  __shared__ __align__(16) u16 Bh[2][4096];
  int t = threadIdx.x, w = t >> 6, l = t & 63;
  int wm = w >> 1, wn = w & 1;
  int lr = l & 15, lks = l >> 4;
  int riw = ((l >> 3) << 1) | (l & 1);
  int kc16s = ((((l >> 1) & 3) ^ ((l >> 3) & 3)) << 3);
  int ar1 = w*16 + riw;
  int sA1c = base + row0 + ar1;      sA1c = sA1c < NSLOT_ ? sA1c : NSLOT_-1;
  int sA2c = base + row0 + 64 + ar1; sA2c = sA2c < NSLOT_ ? sA2c : NSLOT_-1;
  const u16* sAh1 = hidh + ((size_t)sA1c << 10) + kc16s;
  const u16* sAh2 = hidh + ((size_t)sA2c << 10) + kc16s;
  size_t bcol = (size_t)(e*512 + nt*128);
  const u16* sB1 = wdh + ((bcol + (size_t)ar1) << 10) + kc16s;
  const u16* sB2 = wdh + ((bcol + 64 + (size_t)ar1) << 10) + kc16s;
  int aoff[4], boff[4];
  #pragma unroll
  for (int mi = 0; mi < 4; ++mi) aoff[mi] = roff(wm*64 + mi*16 + lr, lks);
  #pragma unroll
  for (int ni = 0; ni < 4; ++ni) boff[ni] = roff(wn*64 + ni*16 + lr, lks);
  f32x4 hh[4][4];
  #pragma unroll
  for (int i = 0; i < 4; ++i)
    #pragma unroll
    for (int j = 0; j < 4; ++j)
      #pragma unroll
      for (int r = 0; r < 4; ++r) hh[i][j][r] = 0.f;
#define STG_DH(buf, kc) do{ \
    gl_lds16(sAh1 + (kc), &Ah[buf][t*8]); \
    gl_lds16(sAh2 + (kc), &Ah[buf][2048 + t*8]); \
    gl_lds16(sB1 + (kc), &Bh[buf][t*8]); \
    gl_lds16(sB2 + (kc), &Bh[buf][2048 + t*8]); }while(0)
  STG_DH(0, 0);
  for (int ks = 0; ks < 32; ++ks){
    int cur = ks & 1;
    __syncthreads();
    if (ks < 31) STG_DH(cur^1, (ks+1)*32);
    f16x8 ah[4], bh[4];
    #pragma unroll
    for (int mi = 0; mi < 4; ++mi) ah[mi] = *(const f16x8*)&Ah[cur][aoff[mi]];
    #pragma unroll
    for (int ni = 0; ni < 4; ++ni) bh[ni] = *(const f16x8*)&Bh[cur][boff[ni]];
    #pragma unroll
    for (int mi = 0; mi < 4; ++mi)
      #pragma unroll
      for (int ni = 0; ni < 4; ++ni)
        hh[mi][ni] = __builtin_amdgcn_mfma_f32_16x16x32_f16(ah[mi], bh[ni], hh[mi][ni], 0, 0, 0);
  }
#undef STG_DH
  #pragma unroll
  for (int mi = 0; mi < 4; ++mi){
    int rb = row0 + wm*64 + mi*16 + lks*4;
    #pragma unroll
    for (int r = 0; r < 4; ++r){
      int rr = rb + r;
      if (rr < cnt){
        float* orow = eo + (((size_t)(base + rr)) << 9) + nt*128;
        #pragma unroll
        for (int ni = 0; ni < 4; ++ni)
          orow[wn*64 + ni*16 + lr] = hh[mi][ni][r];
      }
    }
  }
}

// ---------------- gather + residual (final layer) ----------------
__global__ __launch_bounds__(128) void gather_kernel(const float* __restrict__ xin,
    const float* __restrict__ eo, const int* __restrict__ slot_of, const float* __restrict__ wv,
    float* __restrict__ out){
  int n = blockIdx.x, t = threadIdx.x;
  int s0 = slot_of[2*n], s1 = slot_of[2*n+1];
  double w0 = wv[2*n], w1 = wv[2*n+1];
  float4 xi = *(const float4*)&xin[((size_t)n << 9) + t*4];
  float4 e0 = *(const float4*)&eo[((size_t)s0 << 9) + t*4];
  float4 e1 = *(const float4*)&eo[((size_t)s1 << 9) + t*4];
  float4 o;
  o.x = (float)((double)xi.x + w0*(double)e0.x + w1*(double)e1.x);
  o.y = (float)((double)xi.y + w0*(double)e0.y + w1*(double)e1.y);
  o.z = (float)((double)xi.z + w0*(double)e0.z + w1*(double)e1.z);
  o.w = (float)((double)xi.w + w0*(double)e0.w + w1*(double)e1.w);
  *(float4*)&out[((size_t)n << 9) + t*4] = o;
}

extern "C" void kernel_launch(void* const* d_in, const int* in_sizes, int n_in,
                              void* d_out, int out_size, void* d_ws, size_t ws_size,
                              hipStream_t stream) {
  (void)in_sizes; (void)n_in; (void)out_size; (void)ws_size;
  const float* x0   = (const float*)d_in[0];
  const int*   sid  = (const int*)  d_in[1];
  const float* ln_g = (const float*)d_in[2];
  const float* ln_b = (const float*)d_in[3];
  const float* semb = (const float*)d_in[4];
  const float* h1w  = (const float*)d_in[5];
  const float* h1b  = (const float*)d_in[6];
  const float* h2w  = (const float*)d_in[7];
  const float* h2b  = (const float*)d_in[8];
  const float* s1w  = (const float*)d_in[9];
  const float* s1b  = (const float*)d_in[10];
  const float* s2w  = (const float*)d_in[11];
  const float* s2b  = (const float*)d_in[12];
  const float* g1w  = (const float*)d_in[13];
  const float* g1b  = (const float*)d_in[14];
  const float* g2w  = (const float*)d_in[15];
  const float* g2b  = (const float*)d_in[16];
  const float* wi0  = (const float*)d_in[17];
  const float* wi1  = (const float*)d_in[18];
  const float* wo   = (const float*)d_in[19];

  char* W = (char*)d_ws;
  float*  h      = (float*)(W + 0);                  // 16 MB
  u16*    hfh    = (u16*)  (W + 16777216ULL);        // 8 MB
  u16*    hfl    = (u16*)  (W + 25165824ULL);        // 8 MB
  float*  eo32   = (float*)(W + 167772160ULL);       // 32 MB
  u16*    hid16h = (u16*)  (W + 33554432ULL);        // 32 MB
  u16*    hid16l = (u16*)  (W + 67108864ULL);        // 32 MB
  u16*    w0Th   = (u16*)  (W + 100663296ULL);       // 8 MB each
  u16*    w0Tl   = (u16*)  (W + 109051904ULL);
  u16*    w1Th   = (u16*)  (W + 117440512ULL);
  u16*    w1Tl   = (u16*)  (W + 125829120ULL);
  u16*    woTh   = (u16*)  (W + 134217728ULL);
  u16*    woTl   = (u16*)  (W + 142606336ULL);
  u16*    g1Th   = (u16*)  (W + 150994944ULL);
  u16*    g1Tl   = (u16*)  (W + 151257088ULL);
  double* a64    = (double*)(W + 151584768ULL);
  double* c64    = (double*)(W + 151617536ULL);
  int*    idxa   = (int*)   (W + 151650304ULL);
  float*  warr   = (float*) (W + 151715840ULL);
  int*    tok_of = (int*)   (W + 151781376ULL);
  int*    slot_of= (int*)   (W + 151846912ULL);
  int*    counts = (int*)   (W + 151912448ULL);
  int*    cur    = counts + 8;
  int*    offs   = counts + 16;
  double* partS  = (double*)(W + 152043520ULL);      // 256 KB
  double* partQ  = (double*)(W + 152305664ULL);      // 256 KB

  cvt_all<<<12416, 256, 0, stream>>>(wi0, wi1, wo, g1w,
                                     w0Th, w0Tl, w1Th, w1Tl, woTh, woTl, g1Th, g1Tl);

  // ---- layer 0 ----
  ln_kernel<<<8192, 256, 0, stream>>>(x0, ln_g, ln_b, h);
  colstats<<<512, 256, 0, stream>>>(h, partS, partQ);
  subj_kernel<<<8, 256, 0, stream>>>(sid, semb, h1w, h1b, h2w, h2b, s1w, s1b, s2w, s2b,
                                     partS, partQ, a64, c64, 0);
  hfcast<<<2048, 256, 0, stream>>>(h, a64, c64, hfh, hfl, counts);
  gate2_kernel<<<512, 256, 0, stream>>>(hfh, hfl, g1Th, g1Tl, g1b, g2w, g2b, idxa, warr, counts);
  scatter_kernel<<<32, 256, 0, stream>>>(idxa, counts, cur, offs, tok_of, slot_of);
  up1_kernel<<<16384, 256, 0, stream>>>(hfh, hfl, w0Th, w0Tl, w1Th, w1Tl,
                                        tok_of, offs, counts, hid16h, hid16l);
  down1_kernel<<<4096, 256, 0, stream>>>(hid16h, hid16l, woTh, woTl, offs, counts, eo32);
  gather_ln<<<8192, 128, 0, stream>>>(x0, eo32, slot_of, warr, ln_g + 512, ln_b + 512,
                                      (float*)d_out, h);
  // ---- layer 1 ----
  colstats<<<512, 256, 0, stream>>>(h, partS, partQ);
  subj_kernel<<<8, 256, 0, stream>>>(sid, semb, h1w, h1b, h2w, h2b, s1w, s1b, s2w, s2b,
                                     partS, partQ, a64, c64, 1);
  hfcast<<<2048, 256, 0, stream>>>(h, a64, c64, hfh, hfl, counts);
  gate2_kernel<<<512, 256, 0, stream>>>(hfh, hfl, g1Th, g1Tl, g1b, g2w, g2b, idxa, warr, counts);
  scatter_kernel<<<32, 256, 0, stream>>>(idxa, counts, cur, offs, tok_of, slot_of);
  uph_kernel<<<8192, 256, 0, stream>>>(hfh, w0Th, w1Th, tok_of, offs, counts, hid16h);
  dnh_kernel<<<4096, 256, 0, stream>>>(hid16h, woTh, offs, counts, eo32);
  gather_kernel<<<8192, 128, 0, stream>>>((const float*)d_out, eo32, slot_of, warr, (float*)d_out);
}

// Round 14
// 762.047 us; speedup vs baseline: 1.0619x; 1.0619x over previous
//
#include <hip/hip_runtime.h>

typedef unsigned short u16;
typedef unsigned int   u32;
typedef _Float16       f16;
typedef __attribute__((ext_vector_type(8))) _Float16 f16x8;
typedef __attribute__((ext_vector_type(4))) float    f32x4;
typedef __attribute__((ext_vector_type(4))) double   dbl4;

#define NSLOT_ 16384   // N * K = 8192 * 2

__device__ __forceinline__ u16 f16bits(f16 h){ union{f16 f; u16 u;} x; x.f = h; return x.u; }

__device__ __forceinline__ void gl_lds16(const void* gptr, void* lptr){
  __builtin_amdgcn_global_load_lds((const __attribute__((address_space(1))) u32*)gptr,
                                   (__attribute__((address_space(3))) u32*)lptr, 16, 0, 0);
}

// swizzled LDS offset (u16 units) for row-pair-interleaved layout, BK=32.
__device__ __forceinline__ int roff(int row, int lks){
  return ((row >> 1) << 6) + ((lks ^ ((row >> 1) & 3)) << 4) + ((row & 1) << 3);
}

// ---------------- per-token LayerNorm over D=512 (f64 math, f32 out) ----------------
__global__ __launch_bounds__(256) void ln_kernel(const float* __restrict__ x,
    const float* __restrict__ g, const float* __restrict__ bb, float* __restrict__ h){
  int n = blockIdx.x, t = threadIdx.x;
  const float* xr = x + ((size_t)n << 9);
  float2 v = *(const float2*)&xr[t*2];
  double vx = v.x, vy = v.y;
  double s = vx + vy;
  double q = vx*vx + vy*vy;
  #pragma unroll
  for (int o = 32; o > 0; o >>= 1){ s += __shfl_down(s, o, 64); q += __shfl_down(q, o, 64); }
  __shared__ double ls[4], lq_[4];
  __shared__ double sm, sv;
  int wid = t >> 6, lane = t & 63;
  if (lane == 0){ ls[wid] = s; lq_[wid] = q; }
  __syncthreads();
  if (t == 0){
    double S = ls[0]+ls[1]+ls[2]+ls[3], Q = lq_[0]+lq_[1]+lq_[2]+lq_[3];
    double mean = S * (1.0/512.0);
    double var  = Q * (1.0/512.0) - mean*mean;
    sm = mean; sv = 1.0/sqrt(var + 1e-5);
  }
  __syncthreads();
  double mean = sm, inv = sv;
  int d = t*2;
  float2 o;
  o.x = (float)((vx - mean)*inv*(double)g[d]   + (double)bb[d]);
  o.y = (float)((vy - mean)*inv*(double)g[d+1] + (double)bb[d+1]);
  *(float2*)&h[((size_t)n<<9) + d] = o;
}

// ---------------- fused gather(+residual) for layer l, then LN of layer l+1 ----------------
__global__ __launch_bounds__(128) void gather_ln(const float* __restrict__ xin,
    const float* __restrict__ eo, const int* __restrict__ slot_of, const float* __restrict__ wv,
    const float* __restrict__ g, const float* __restrict__ bb,
    float* __restrict__ out, float* __restrict__ h){
  int n = blockIdx.x, t = threadIdx.x;
  int s0 = slot_of[2*n], s1 = slot_of[2*n+1];
  double w0 = wv[2*n], w1 = wv[2*n+1];
  float4 xi = *(const float4*)&xin[((size_t)n << 9) + t*4];
  float4 e0 = *(const float4*)&eo[((size_t)s0 << 9) + t*4];
  float4 e1 = *(const float4*)&eo[((size_t)s1 << 9) + t*4];
  double o0 = (double)xi.x + w0*(double)e0.x + w1*(double)e1.x;
  double o1 = (double)xi.y + w0*(double)e0.y + w1*(double)e1.y;
  double o2 = (double)xi.z + w0*(double)e0.z + w1*(double)e1.z;
  double o3 = (double)xi.w + w0*(double)e0.w + w1*(double)e1.w;
  float4 o; o.x = (float)o0; o.y = (float)o1; o.z = (float)o2; o.w = (float)o3;
  *(float4*)&out[((size_t)n << 9) + t*4] = o;
  double vx = o.x, vy = o.y, vz = o.z, vw = o.w;
  double s = vx+vy+vz+vw;
  double q = vx*vx+vy*vy+vz*vz+vw*vw;
  #pragma unroll
  for (int off = 32; off > 0; off >>= 1){ s += __shfl_down(s, off, 64); q += __shfl_down(q, off, 64); }
  __shared__ double ls[2], lq_[2];
  __shared__ double sm, sv;
  int wid = t >> 6, lane = t & 63;
  if (lane == 0){ ls[wid] = s; lq_[wid] = q; }
  __syncthreads();
  if (t == 0){
    double S = ls[0]+ls[1], Q = lq_[0]+lq_[1];
    double mean = S * (1.0/512.0);
    double var  = Q * (1.0/512.0) - mean*mean;
    sm = mean; sv = 1.0/sqrt(var + 1e-5);
  }
  __syncthreads();
  double mean = sm, inv = sv;
  int d = t*4;
  float4 ho;
  ho.x = (float)((vx - mean)*inv*(double)g[d]   + (double)bb[d]);
  ho.y = (float)((vy - mean)*inv*(double)g[d+1] + (double)bb[d+1]);
  ho.z = (float)((vz - mean)*inv*(double)g[d+2] + (double)bb[d+2]);
  ho.w = (float)((vw - mean)*inv*(double)g[d+3] + (double)bb[d+3]);
  *(float4*)&h[((size_t)n<<9) + d] = ho;
}

// ---------------- column stats, stage 1: partials over 128-row T-chunks ----------------
// grid 512 = b(8) x colchunk(8) x tchunk(8)
__global__ __launch_bounds__(256) void colstats(const float* __restrict__ h,
    double* __restrict__ pS, double* __restrict__ pQ){
  int bid = blockIdx.x;
  int b  = bid >> 6;
  int ch = (bid >> 3) & 7;
  int tc = bid & 7;
  int t = threadIdx.x;
  int col = ch*64 + (t & 63);
  int tp = t >> 6;
  const float* base = h + ((size_t)b << 19) + ((size_t)(tc*128) << 9);
  double s = 0.0, q = 0.0;
  for (int tt = tp; tt < 128; tt += 4){
    double v = (double)base[((size_t)tt << 9) + col];
    s += v; q += v*v;
  }
  __shared__ double ls[4][64], lq[4][64];
  ls[tp][t & 63] = s; lq[tp][t & 63] = q;
  __syncthreads();
  if (tp == 0){
    double S = ls[0][t]+ls[1][t]+ls[2][t]+ls[3][t];
    double Q = lq[0][t]+lq[1][t]+lq[2][t]+lq[3][t];
    pS[((tc<<3)+b)*512 + col] = S;
    pQ[((tc<<3)+b)*512 + col] = Q;
  }
}

// ---------------- subject MLP -> per-(b,d) affine a,c (f64); reduces colstat partials ----------------
__global__ __launch_bounds__(256) void subj_kernel(const int* __restrict__ sid,
    const float* __restrict__ semb,
    const float* __restrict__ h1w, const float* __restrict__ h1b,
    const float* __restrict__ h2w, const float* __restrict__ h2b,
    const float* __restrict__ s1w, const float* __restrict__ s1b,
    const float* __restrict__ s2w, const float* __restrict__ s2b,
    const double* __restrict__ pS, const double* __restrict__ pQ,
    double* __restrict__ a64, double* __restrict__ c64, int l){
  __shared__ double ev[64], hid1[128], hh[128], sh[64], sp[1024];
  __shared__ double cs_s[512], cq_s[512];
  int t = threadIdx.x;
  int b = blockIdx.x;
  for (int d = t; d < 512; d += 256){
    double S = 0.0, Q = 0.0;
    #pragma unroll
    for (int tc = 0; tc < 8; ++tc){
      S += pS[((tc<<3)+b)*512 + d];
      Q += pQ[((tc<<3)+b)*512 + d];
    }
    cs_s[d] = S; cq_s[d] = Q;
  }
  int s = sid[b];
  if (t < 64) ev[t] = (double)semb[l*4096 + s*64 + t];
  __syncthreads();
  if (t < 128){
    double acc = (double)h1b[l*128 + t];
    for (int i = 0; i < 64; ++i) acc += ev[i]*(double)h1w[l*8192 + i*128 + t];
    hid1[t] = acc > 0.0 ? acc : 0.0;
  }
  __syncthreads();
  if (t < 128){
    double acc = (double)h2b[l*128 + t];
    for (int i = 0; i < 128; ++i) acc += hid1[i]*(double)h2w[l*16384 + i*128 + t];
    hh[t] = acc;
  }
  __syncthreads();
  if (t < 64){
    double acc = (double)s1b[l*64 + t];
    for (int i = 0; i < 128; ++i) acc += hh[i]*(double)s1w[l*8192 + i*64 + t];
    sh[t] = acc > 0.0 ? acc : 0.0;
  }
  __syncthreads();
  for (int m = t; m < 1024; m += 256){
    double acc = (double)s2b[l*1024 + m];
    for (int j = 0; j < 64; ++j) acc += sh[j]*(double)s2w[l*65536 + j*1024 + m];
    sp[m] = acc;
  }
  __syncthreads();
  for (int d = t; d < 512; d += 256){
    double mu  = cs_s[d] * (1.0/1024.0);
    double var = cq_s[d] * (1.0/1024.0) - mu*mu;
    double inv = 1.0/sqrt(var + 1e-8);
    double spv = sp[d];
    double gamma = (spv > 30.0 ? spv : log1p(exp(spv))) + 1e-8;
    double beta  = sp[512 + d];
    double A = gamma * inv;
    a64[(b<<9)+d] = A;
    c64[(b<<9)+d] = beta - mu*A;
  }
}

// ---------------- hf = h*a + c -> fp16 hi/lo' (lo scaled 2^11); block 0 zeros counts/cur ----------------
__global__ __launch_bounds__(256) void hfcast(const float* __restrict__ h,
    const double* __restrict__ a64, const double* __restrict__ c64,
    u16* __restrict__ hfh, u16* __restrict__ hfl, int* __restrict__ counts){
  if (blockIdx.x == 0 && threadIdx.x < 16) counts[threadIdx.x] = 0;
  size_t i0 = ((size_t)blockIdx.x*256 + threadIdx.x) * 8;
  int n = (int)(i0 >> 9);
  int d0 = (int)(i0 & 511);
  int b = n >> 10;
  float4 x0 = *(const float4*)&h[i0];
  float4 x1 = *(const float4*)&h[i0 + 4];
  dbl4 a0 = *(const dbl4*)&a64[(b<<9) + d0];
  dbl4 a1 = *(const dbl4*)&a64[(b<<9) + d0 + 4];
  dbl4 c0 = *(const dbl4*)&c64[(b<<9) + d0];
  dbl4 c1 = *(const dbl4*)&c64[(b<<9) + d0 + 4];
  float f[8];
  f[0] = (float)((double)x0.x*a0[0] + c0[0]);
  f[1] = (float)((double)x0.y*a0[1] + c0[1]);
  f[2] = (float)((double)x0.z*a0[2] + c0[2]);
  f[3] = (float)((double)x0.w*a0[3] + c0[3]);
  f[4] = (float)((double)x1.x*a1[0] + c1[0]);
  f[5] = (float)((double)x1.y*a1[1] + c1[1]);
  f[6] = (float)((double)x1.z*a1[2] + c1[2]);
  f[7] = (float)((double)x1.w*a1[3] + c1[3]);
  ushort4 oh0, oh1, ol0, ol1;
  u16 vh[8], vl[8];
  #pragma unroll
  for (int j = 0; j < 8; ++j){
    f16 hi = (f16)f[j];
    float rem = (f[j] - (float)hi) * 2048.f;
    f16 lo = (f16)rem;
    vh[j] = f16bits(hi); vl[j] = f16bits(lo);
  }
  oh0.x=vh[0]; oh0.y=vh[1]; oh0.z=vh[2]; oh0.w=vh[3];
  oh1.x=vh[4]; oh1.y=vh[5]; oh1.z=vh[6]; oh1.w=vh[7];
  ol0.x=vl[0]; ol0.y=vl[1]; ol0.z=vl[2]; ol0.w=vl[3];
  ol1.x=vl[4]; ol1.y=vl[5]; ol1.z=vl[6]; ol1.w=vl[7];
  *(ushort4*)&hfh[i0]   = oh0;
  *(ushort4*)&hfh[i0+4] = oh1;
  *(ushort4*)&hfl[i0]   = ol0;
  *(ushort4*)&hfl[i0+4] = ol1;
}

// ---------------- gating: fp16-split MFMA (f32 accum) + f64 finish (split-k g2), top-2 ----------------
__global__ __launch_bounds__(256) void gate2_kernel(const u16* __restrict__ hfh,
    const u16* __restrict__ hfl, const u16* __restrict__ g1Th, const u16* __restrict__ g1Tl,
    const float* __restrict__ g1b, const float* __restrict__ g2w, const float* __restrict__ g2b,
    int* __restrict__ idxo, float* __restrict__ wo_, int* __restrict__ counts){
  __shared__ double hid_s[16][258];
  __shared__ double lg[16*8];
  __shared__ double lg2[256];
  __shared__ int lcnt[8];
  int t = threadIdx.x, w = t >> 6, l = t & 63;
  int tok0 = blockIdx.x << 4;
  if (t < 8) lcnt[t] = 0;
  int lr = l & 15, lks = l >> 4;
  const u16* ahp = hfh + ((size_t)(tok0 + lr) << 9) + lks*8;
  const u16* alp = hfl + ((size_t)(tok0 + lr) << 9) + lks*8;
  const u16* bhp[4]; const u16* blp[4];
  #pragma unroll
  for (int nf = 0; nf < 4; ++nf){
    int col = w*64 + nf*16 + lr;
    bhp[nf] = g1Th + ((size_t)col << 9) + lks*8;
    blp[nf] = g1Tl + ((size_t)col << 9) + lks*8;
  }
  f32x4 hh[4], cr[4];
  #pragma unroll
  for (int nf = 0; nf < 4; ++nf)
    #pragma unroll
    for (int r = 0; r < 4; ++r){ hh[nf][r] = 0.f; cr[nf][r] = 0.f; }
  f16x8 ah = *(const f16x8*)ahp;
  f16x8 al = *(const f16x8*)alp;
  for (int kc = 0; kc < 512; kc += 32){
    int kn = (kc + 32) & 511;
    f16x8 ahn = *(const f16x8*)(ahp + kn);
    f16x8 aln = *(const f16x8*)(alp + kn);
    #pragma unroll
    for (int nf = 0; nf < 4; ++nf){
      f16x8 bh = *(const f16x8*)(bhp[nf] + kc);
      f16x8 bl = *(const f16x8*)(blp[nf] + kc);
      hh[nf] = __builtin_amdgcn_mfma_f32_16x16x32_f16(ah, bh, hh[nf], 0, 0, 0);
      cr[nf] = __builtin_amdgcn_mfma_f32_16x16x32_f16(ah, bl, cr[nf], 0, 0, 0);
      cr[nf] = __builtin_amdgcn_mfma_f32_16x16x32_f16(al, bh, cr[nf], 0, 0, 0);
    }
    ah = ahn; al = aln;
  }
  #pragma unroll
  for (int nf = 0; nf < 4; ++nf){
    int col = w*64 + nf*16 + lr;
    double gb = (double)g1b[col];
    #pragma unroll
    for (int r = 0; r < 4; ++r){
      int row = lks*4 + r;
      double v = (double)hh[nf][r] + (double)cr[nf][r]*(1.0/2048.0) + gb;
      hid_s[row][col] = v > 0.0 ? v : 0.0;
    }
  }
  __syncthreads();
  {
    int pair = t >> 1, kh = t & 1;
    int tok = pair >> 3, e = pair & 7;
    double la = kh ? 0.0 : (double)g2b[e];
    int k0 = kh << 7;
    for (int k = k0; k < k0 + 128; ++k) la += hid_s[tok][k]*(double)g2w[(k<<3)+e];
    lg2[t] = la;
  }
  __syncthreads();
  if (t < 128) lg[t] = lg2[2*t] + lg2[2*t+1];
  __syncthreads();
  if (t < 16){
    double l0[8];
    #pragma unroll
    for (int e = 0; e < 8; ++e) l0[e] = lg[(t<<3)+e];
    double m = l0[0];
    #pragma unroll
    for (int e = 1; e < 8; ++e) m = fmax(m, l0[e]);
    double p[8]; double s = 0.0;
    #pragma unroll
    for (int e = 0; e < 8; ++e){ p[e] = exp(l0[e]-m); s += p[e]; }
    double b1 = -1e300, b2 = -1e300; int i1 = 0, i2 = 1;
    #pragma unroll
    for (int e = 0; e < 8; ++e){
      double v = l0[e];
      if (v > b1){ b2 = b1; i2 = i1; b1 = v; i1 = e; }
      else if (v > b2){ b2 = v; i2 = e; }
    }
    double pr1 = p[i1]/s, pr2 = p[i2]/s;
    double den = pr1 + pr2 + 1e-8;
    int n = tok0 + t;
    idxo[2*n] = i1; idxo[2*n+1] = i2;
    wo_[2*n] = (float)(pr1/den); wo_[2*n+1] = (float)(pr2/den);
    atomicAdd(&lcnt[i1], 1); atomicAdd(&lcnt[i2], 1);
  }
  __syncthreads();
  if (t < 8) atomicAdd(&counts[t], lcnt[t]);
}

// ---------------- scatter (computes offs locally from final counts; block 0 publishes) ----------------
__global__ __launch_bounds__(256) void scatter_kernel(const int* __restrict__ idx,
    const int* __restrict__ counts, int* __restrict__ cur,
    int* __restrict__ offs, int* __restrict__ tok_of, int* __restrict__ slot_of){
  __shared__ int lcnt[8], lbase[8], offs_s[8];
  int t = threadIdx.x;
  int n = blockIdx.x*256 + t;
  if (t < 8) lcnt[t] = 0;
  if (t == 0){
    int run = 0;
    for (int e = 0; e < 8; ++e){ offs_s[e] = run; run += counts[e]; }
  }
  __syncthreads();
  if (blockIdx.x == 0 && t < 8) offs[t] = offs_s[t];
  int e0 = idx[2*n], e1 = idx[2*n+1];
  int p0 = atomicAdd(&lcnt[e0], 1);
  int p1 = atomicAdd(&lcnt[e1], 1);
  __syncthreads();
  if (t < 8) lbase[t] = atomicAdd(&cur[t], lcnt[t]);
  __syncthreads();
  int s0 = offs_s[e0] + lbase[e0] + p0;
  int s1 = offs_s[e1] + lbase[e1] + p1;
  tok_of[s0] = n; tok_of[s1] = n;
  slot_of[2*n] = s0; slot_of[2*n+1] = s1;
}

// ---------------- merged weight transpose + fp16 hi/lo' split (all 4 weights, 1 launch) ----------------
__device__ __forceinline__ void cvt_tile(const float* __restrict__ src,
    u16* __restrict__ dh, u16* __restrict__ dl, int R, int C, int bx){
  int tilesC = C >> 5, tilesR = R >> 5;
  int e = bx / (tilesR*tilesC);
  int rem = bx % (tilesR*tilesC);
  int rt = rem / tilesC, ct = rem % tilesC;
  __shared__ float tile[32][33];
  int t = threadIdx.x;
  int j = t & 31, i0 = t >> 5;
  const float* s = src + (size_t)e*R*C + (size_t)(rt*32)*C + ct*32;
  for (int ii = i0; ii < 32; ii += 8) tile[ii][j] = s[(size_t)ii*C + j];
  __syncthreads();
  size_t ob = (size_t)e*R*C + (size_t)(ct*32)*R + rt*32;
  for (int ii = i0; ii < 32; ii += 8){
    float v = tile[j][ii];
    f16 hi = (f16)v;
    float rem2 = (v - (float)hi) * 2048.f;
    f16 lo = (f16)rem2;
    dh[ob + (size_t)ii*R + j] = f16bits(hi);
    dl[ob + (size_t)ii*R + j] = f16bits(lo);
  }
}

__global__ __launch_bounds__(256) void cvt_all(const float* __restrict__ wi0,
    const float* __restrict__ wi1, const float* __restrict__ wo, const float* __restrict__ g1w,
    u16* __restrict__ w0Th, u16* __restrict__ w0Tl, u16* __restrict__ w1Th, u16* __restrict__ w1Tl,
    u16* __restrict__ woTh, u16* __restrict__ woTl, u16* __restrict__ g1Th, u16* __restrict__ g1Tl){
  int bx = blockIdx.x;
  if (bx < 4096)       cvt_tile(wi0, w0Th, w0Tl, 512, 1024, bx);
  else if (bx < 8192)  cvt_tile(wi1, w1Th, w1Tl, 512, 1024, bx - 4096);
  else if (bx < 12288) cvt_tile(wo,  woTh, woTl, 1024, 512, bx - 8192);
  else                 cvt_tile(g1w, g1Th, g1Tl, 512, 256,  bx - 12288);
}

// ---------------- layer-1 up-GEMM: fp16-split, 128r x 64c, all-LDS swizzled (r12) ----------------
// grid: e(8) x mt(128) x nt(16)
__global__ __launch_bounds__(256) void up1_kernel(const u16* __restrict__ hfh,
    const u16* __restrict__ hfl,
    const u16* __restrict__ w0h, const u16* __restrict__ w0l,
    const u16* __restrict__ w1h, const u16* __restrict__ w1l,
    const int* __restrict__ tok_of, const int* __restrict__ offs, const int* __restrict__ counts,
    u16* __restrict__ hidh, u16* __restrict__ hidl){
  int bx = blockIdx.x;
  int e  = bx >> 11;
  int mt = (bx >> 4) & 127;
  int nt = bx & 15;
  int base = offs[e], cnt = counts[e];
  int row0 = mt << 7;
  if (row0 >= cnt) return;
  __shared__ __align__(16) u16 Ah[2][4096], Alo[2][4096];
  __shared__ __align__(16) u16 B0h[2][2048], B0l[2][2048], B1h[2][2048], B1l[2][2048];
  int t = threadIdx.x, w = t >> 6, l = t & 63;
  int wm = w >> 1, wn = w & 1;
  int lr = l & 15, lks = l >> 4;
  int riw = ((l >> 3) << 1) | (l & 1);
  int kc16s = ((((l >> 1) & 3) ^ ((l >> 3) & 3)) << 3);
  int ar1 = w*16 + riw;
  int tokA1, tokA2;
  { int ss = base + row0 + ar1;      ss = ss < NSLOT_ ? ss : NSLOT_-1; tokA1 = tok_of[ss]; }
  { int ss = base + row0 + 64 + ar1; ss = ss < NSLOT_ ? ss : NSLOT_-1; tokA2 = tok_of[ss]; }
  const u16* sAh1 = hfh + ((size_t)tokA1 << 9) + kc16s;
  const u16* sAh2 = hfh + ((size_t)tokA2 << 9) + kc16s;
  const u16* sAl1 = hfl + ((size_t)tokA1 << 9) + kc16s;
  const u16* sAl2 = hfl + ((size_t)tokA2 << 9) + kc16s;
  size_t bcol = (size_t)(e*1024 + nt*64);
  size_t bci = (bcol + (size_t)ar1) << 9;
  const u16* sB0h = w0h + bci + kc16s;
  const u16* sB0l = w0l + bci + kc16s;
  const u16* sB1h = w1h + bci + kc16s;
  const u16* sB1l = w1l + bci + kc16s;
  int aoff[4], boff[2];
  #pragma unroll
  for (int mi = 0; mi < 4; ++mi) aoff[mi] = roff(wm*64 + mi*16 + lr, lks);
  #pragma unroll
  for (int ni = 0; ni < 2; ++ni) boff[ni] = roff(wn*32 + ni*16 + lr, lks);
  f32x4 hh0[4][2], cr0[4][2], hh1[4][2], cr1[4][2];
  #pragma unroll
  for (int i = 0; i < 4; ++i)
    #pragma unroll
    for (int j = 0; j < 2; ++j)
      #pragma unroll
      for (int r = 0; r < 4; ++r){ hh0[i][j][r]=0.f; cr0[i][j][r]=0.f; hh1[i][j][r]=0.f; cr1[i][j][r]=0.f; }
#define STG_U(buf, kc) do{ \
    gl_lds16(sAh1 + (kc), &Ah[buf][t*8]); \
    gl_lds16(sAh2 + (kc), &Ah[buf][2048 + t*8]); \
    gl_lds16(sAl1 + (kc), &Alo[buf][t*8]); \
    gl_lds16(sAl2 + (kc), &Alo[buf][2048 + t*8]); \
    gl_lds16(sB0h + (kc), &B0h[buf][t*8]); \
    gl_lds16(sB0l + (kc), &B0l[buf][t*8]); \
    gl_lds16(sB1h + (kc), &B1h[buf][t*8]); \
    gl_lds16(sB1l + (kc), &B1l[buf][t*8]); }while(0)
  STG_U(0, 0);
  for (int ks = 0; ks < 16; ++ks){
    int cur = ks & 1;
    __syncthreads();
    if (ks < 15) STG_U(cur^1, (ks+1)*32);
    f16x8 ah[4], al[4], b0hv[2], b0lv[2], b1hv[2], b1lv[2];
    #pragma unroll
    for (int mi = 0; mi < 4; ++mi){
      ah[mi] = *(const f16x8*)&Ah[cur][aoff[mi]];
      al[mi] = *(const f16x8*)&Alo[cur][aoff[mi]];
    }
    #pragma unroll
    for (int ni = 0; ni < 2; ++ni){
      b0hv[ni] = *(const f16x8*)&B0h[cur][boff[ni]];
      b0lv[ni] = *(const f16x8*)&B0l[cur][boff[ni]];
      b1hv[ni] = *(const f16x8*)&B1h[cur][boff[ni]];
      b1lv[ni] = *(const f16x8*)&B1l[cur][boff[ni]];
    }
    #pragma unroll
    for (int mi = 0; mi < 4; ++mi)
      #pragma unroll
      for (int ni = 0; ni < 2; ++ni){
        hh0[mi][ni] = __builtin_amdgcn_mfma_f32_16x16x32_f16(ah[mi], b0hv[ni], hh0[mi][ni], 0, 0, 0);
        hh1[mi][ni] = __builtin_amdgcn_mfma_f32_16x16x32_f16(ah[mi], b1hv[ni], hh1[mi][ni], 0, 0, 0);
        cr0[mi][ni] = __builtin_amdgcn_mfma_f32_16x16x32_f16(ah[mi], b0lv[ni], cr0[mi][ni], 0, 0, 0);
        cr0[mi][ni] = __builtin_amdgcn_mfma_f32_16x16x32_f16(al[mi], b0hv[ni], cr0[mi][ni], 0, 0, 0);
        cr1[mi][ni] = __builtin_amdgcn_mfma_f32_16x16x32_f16(ah[mi], b1lv[ni], cr1[mi][ni], 0, 0, 0);
        cr1[mi][ni] = __builtin_amdgcn_mfma_f32_16x16x32_f16(al[mi], b1hv[ni], cr1[mi][ni], 0, 0, 0);
      }
  }
#undef STG_U
  #pragma unroll
  for (int mi = 0; mi < 4; ++mi){
    int rb = row0 + wm*64 + mi*16 + lks*4;
    #pragma unroll
    for (int r = 0; r < 4; ++r){
      int rr = rb + r;
      if (rr < cnt){
        size_t orow = ((size_t)(base + rr) << 10) + nt*64;
        #pragma unroll
        for (int ni = 0; ni < 2; ++ni){
          int col = wn*32 + ni*16 + lr;
          float u0 = hh0[mi][ni][r] + cr0[mi][ni][r]*(1.f/2048.f);
          float u1 = hh1[mi][ni][r] + cr1[mi][ni][r]*(1.f/2048.f);
          u0 = u0 > 0.f ? u0 : 0.f;
          float v = u0*u1;
          f16 vh = (f16)v;
          float rem = (v - (float)vh)*2048.f;
          hidh[orow + col] = f16bits(vh);
          hidl[orow + col] = f16bits((f16)rem);
        }
      }
    }
  }
}

// ---------------- layer-1 down-GEMM: fp16-split, 128r x 64c, all-LDS swizzled (r12) ----------------
// grid: e(8) x mt(128) x nt(8)
__global__ __launch_bounds__(256) void down1_kernel(const u16* __restrict__ hidh,
    const u16* __restrict__ hidl, const u16* __restrict__ wdh, const u16* __restrict__ wdl,
    const int* __restrict__ offs, const int* __restrict__ counts, float* __restrict__ eo){
  int bx = blockIdx.x;
  int e  = bx >> 10;
  int mt = (bx >> 3) & 127;
  int nt = bx & 7;
  int base = offs[e], cnt = counts[e];
  int row0 = mt << 7;
  if (row0 >= cnt) return;
  __shared__ __align__(16) u16 Ah[2][4096], Alo[2][4096];
  __shared__ __align__(16) u16 Bh[2][2048], Bl[2][2048];
  int t = threadIdx.x, w = t >> 6, l = t & 63;
  int wm = w >> 1, wn = w & 1;
  int lr = l & 15, lks = l >> 4;
  int riw = ((l >> 3) << 1) | (l & 1);
  int kc16s = ((((l >> 1) & 3) ^ ((l >> 3) & 3)) << 3);
  int ar1 = w*16 + riw;
  int sA1c = base + row0 + ar1;      sA1c = sA1c < NSLOT_ ? sA1c : NSLOT_-1;
  int sA2c = base + row0 + 64 + ar1; sA2c = sA2c < NSLOT_ ? sA2c : NSLOT_-1;
  const u16* sAh1 = hidh + ((size_t)sA1c << 10) + kc16s;
  const u16* sAh2 = hidh + ((size_t)sA2c << 10) + kc16s;
  const u16* sAl1 = hidl + ((size_t)sA1c << 10) + kc16s;
  const u16* sAl2 = hidl + ((size_t)sA2c << 10) + kc16s;
  size_t bcol = (size_t)(e*512 + nt*64);
  size_t bci = (bcol + (size_t)ar1) << 10;
  const u16* sBh = wdh + bci + kc16s;
  const u16* sBl = wdl + bci + kc16s;
  int aoff[4], boff[2];
  #pragma unroll
  for (int mi = 0; mi < 4; ++mi) aoff[mi] = roff(wm*64 + mi*16 + lr, lks);
  #pragma unroll
  for (int ni = 0; ni < 2; ++ni) boff[ni] = roff(wn*32 + ni*16 + lr, lks);
  f32x4 hh[4][2], cr[4][2];
  #pragma unroll
  for (int i = 0; i < 4; ++i)
    #pragma unroll
    for (int j = 0; j < 2; ++j)
      #pragma unroll
      for (int r = 0; r < 4; ++r){ hh[i][j][r]=0.f; cr[i][j][r]=0.f; }
#define STG_D(buf, kc) do{ \
    gl_lds16(sAh1 + (kc), &Ah[buf][t*8]); \
    gl_lds16(sAh2 + (kc), &Ah[buf][2048 + t*8]); \
    gl_lds16(sAl1 + (kc), &Alo[buf][t*8]); \
    gl_lds16(sAl2 + (kc), &Alo[buf][2048 + t*8]); \
    gl_lds16(sBh + (kc), &Bh[buf][t*8]); \
    gl_lds16(sBl + (kc), &Bl[buf][t*8]); }while(0)
  STG_D(0, 0);
  for (int ks = 0; ks < 32; ++ks){
    int cur = ks & 1;
    __syncthreads();
    if (ks < 31) STG_D(cur^1, (ks+1)*32);
    f16x8 ah[4], al[4], bh[2], bl[2];
    #pragma unroll
    for (int mi = 0; mi < 4; ++mi){
      ah[mi] = *(const f16x8*)&Ah[cur][aoff[mi]];
      al[mi] = *(const f16x8*)&Alo[cur][aoff[mi]];
    }
    #pragma unroll
    for (int ni = 0; ni < 2; ++ni){
      bh[ni] = *(const f16x8*)&Bh[cur][boff[ni]];
      bl[ni] = *(const f16x8*)&Bl[cur][boff[ni]];
    }
    #pragma unroll
    for (int mi = 0; mi < 4; ++mi)
      #pragma unroll
      for (int ni = 0; ni < 2; ++ni){
        hh[mi][ni] = __builtin_amdgcn_mfma_f32_16x16x32_f16(ah[mi], bh[ni], hh[mi][ni], 0, 0, 0);
        cr[mi][ni] = __builtin_amdgcn_mfma_f32_16x16x32_f16(ah[mi], bl[ni], cr[mi][ni], 0, 0, 0);
        cr[mi][ni] = __builtin_amdgcn_mfma_f32_16x16x32_f16(al[mi], bh[ni], cr[mi][ni], 0, 0, 0);
      }
  }
#undef STG_D
  #pragma unroll
  for (int mi = 0; mi < 4; ++mi){
    int rb = row0 + wm*64 + mi*16 + lks*4;
    #pragma unroll
    for (int r = 0; r < 4; ++r){
      int rr = rb + r;
      if (rr < cnt){
        float* orow = eo + (((size_t)(base + rr)) << 9) + nt*64;
        #pragma unroll
        for (int ni = 0; ni < 2; ++ni)
          orow[wn*32 + ni*16 + lr] = hh[mi][ni][r] + cr[mi][ni][r]*(1.f/2048.f);
      }
    }
  }
}

// ---------------- layer-2 up-GEMM: fp16 hi-only, 128r x 128c; waves 2x2 (r12) ----------------
// grid: e(8) x mt(128) x nt(8)
__global__ __launch_bounds__(256) void uph_kernel(const u16* __restrict__ hfh,
    const u16* __restrict__ w0h, const u16* __restrict__ w1h,
    const int* __restrict__ tok_of, const int* __restrict__ offs, const int* __restrict__ counts,
    u16* __restrict__ hidh){
  int bx = blockIdx.x;
  int e  = bx >> 10;
  int mt = (bx >> 3) & 127;
  int nt = bx & 7;
  int base = offs[e], cnt = counts[e];
  int row0 = mt << 7;
  if (row0 >= cnt) return;
  __shared__ __align__(16) u16 Ah[2][4096];
  __shared__ __align__(16) u16 B0[2][4096], B1[2][4096];
  int t = threadIdx.x, w = t >> 6, l = t & 63;
  int wm = w >> 1, wn = w & 1;
  int lr = l & 15, lks = l >> 4;
  int riw = ((l >> 3) << 1) | (l & 1);
  int kc16s = ((((l >> 1) & 3) ^ ((l >> 3) & 3)) << 3);
  int ar1 = w*16 + riw;
  int tokA1, tokA2;
  { int ss = base + row0 + ar1;      ss = ss < NSLOT_ ? ss : NSLOT_-1; tokA1 = tok_of[ss]; }
  { int ss = base + row0 + 64 + ar1; ss = ss < NSLOT_ ? ss : NSLOT_-1; tokA2 = tok_of[ss]; }
  const u16* sAh1 = hfh + ((size_t)tokA1 << 9) + kc16s;
  const u16* sAh2 = hfh + ((size_t)tokA2 << 9) + kc16s;
  size_t bcol = (size_t)(e*1024 + nt*128);
  const u16* sB0a = w0h + ((bcol + (size_t)ar1) << 9) + kc16s;
  const u16* sB0b = w0h + ((bcol + 64 + (size_t)ar1) << 9) + kc16s;
  const u16* sB1a = w1h + ((bcol + (size_t)ar1) << 9) + kc16s;
  const u16* sB1b = w1h + ((bcol + 64 + (size_t)ar1) << 9) + kc16s;
  int aoff[4], boff[4];
  #pragma unroll
  for (int mi = 0; mi < 4; ++mi) aoff[mi] = roff(wm*64 + mi*16 + lr, lks);
  #pragma unroll
  for (int ni = 0; ni < 4; ++ni) boff[ni] = roff(wn*64 + ni*16 + lr, lks);
  f32x4 hh0[4][4], hh1[4][4];
  #pragma unroll
  for (int i = 0; i < 4; ++i)
    #pragma unroll
    for (int j = 0; j < 4; ++j)
      #pragma unroll
      for (int r = 0; r < 4; ++r){ hh0[i][j][r]=0.f; hh1[i][j][r]=0.f; }
#define STG_UH(buf, kc) do{ \
    gl_lds16(sAh1 + (kc), &Ah[buf][t*8]); \
    gl_lds16(sAh2 + (kc), &Ah[buf][2048 + t*8]); \
    gl_lds16(sB0a + (kc), &B0[buf][t*8]); \
    gl_lds16(sB0b + (kc), &B0[buf][2048 + t*8]); \
    gl_lds16(sB1a + (kc), &B1[buf][t*8]); \
    gl_lds16(sB1b + (kc), &B1[buf][2048 + t*8]); }while(0)
  STG_UH(0, 0);
  for (int ks = 0; ks < 16; ++ks){
    int cur = ks & 1;
    __syncthreads();
    if (ks < 15) STG_UH(cur^1, (ks+1)*32);
    f16x8 ah[4], b0v[4], b1v[4];
    #pragma unroll
    for (int mi = 0; mi < 4; ++mi) ah[mi] = *(const f16x8*)&Ah[cur][aoff[mi]];
    #pragma unroll
    for (int ni = 0; ni < 4; ++ni){
      b0v[ni] = *(const f16x8*)&B0[cur][boff[ni]];
      b1v[ni] = *(const f16x8*)&B1[cur][boff[ni]];
    }
    #pragma unroll
    for (int mi = 0; mi < 4; ++mi)
      #pragma unroll
      for (int ni = 0; ni < 4; ++ni){
        hh0[mi][ni] = __builtin_amdgcn_mfma_f32_16x16x32_f16(ah[mi], b0v[ni], hh0[mi][ni], 0, 0, 0);
        hh1[mi][ni] = __builtin_amdgcn_mfma_f32_16x16x32_f16(ah[mi], b1v[ni], hh1[mi][ni], 0, 0, 0);
      }
  }
#undef STG_UH
  #pragma unroll
  for (int mi = 0; mi < 4; ++mi){
    int rb = row0 + wm*64 + mi*16 + lks*4;
    #pragma unroll
    for (int r = 0; r < 4; ++r){
      int rr = rb + r;
      if (rr < cnt){
        size_t orow = ((size_t)(base + rr) << 10) + nt*128;
        #pragma unroll
        for (int ni = 0; ni < 4; ++ni){
          int col = wn*64 + ni*16 + lr;
          float u0 = hh0[mi][ni][r];
          u0 = u0 > 0.f ? u0 : 0.f;
          hidh[orow + col] = f16bits((f16)(u0*hh1[mi][ni][r]));
        }
      }
    }
  }
}

// ---------------- layer-2 down-GEMM: fp16 hi-only, 128r x 128c; waves 2x2 (r12) ----------------
// grid: e(8) x mt(128) x nt(4)
__global__ __launch_bounds__(256) void dnh_kernel(const u16* __restrict__ hidh,
    const u16* __restrict__ wdh,
    const int* __restrict__ offs, const int* __restrict__ counts, float* __restrict__ eo){
  int bx = blockIdx.x;
  int e  = bx >> 9;
  int mt = (bx >> 2) & 127;
  int nt = bx & 3;
  int base = offs[e], cnt = counts[e];
  int row0 = mt << 7;
  if (row0 >= cnt) return;
  __shared__ __align__(16) u16 Ah[2][4096];
  __shared__ __align__(16) u16 Bh[2][4096];
  int t = threadIdx.x, w = t >> 6, l = t & 63;
  int wm = w >> 1, wn = w & 1;
  int lr = l & 15, lks = l >> 4;
  int riw = ((l >> 3) << 1) | (l & 1);
  int kc16s = ((((l >> 1) & 3) ^ ((l >> 3) & 3)) << 3);
  int ar1 = w*16 + riw;
  int sA1c = base + row0 + ar1;      sA1c = sA1c < NSLOT_ ? sA1c : NSLOT_-1;
  int sA2c = base + row0 + 64 + ar1; sA2c = sA2c < NSLOT_ ? sA2c : NSLOT_-1;
  const u16* sAh1 = hidh + ((size_t)sA1c << 10) + kc16s;
  const u16* sAh2 = hidh + ((size_t)sA2c << 10) + kc16s;
  size_t bcol = (size_t)(e*512 + nt*128);
  const u16* sB1 = wdh + ((bcol + (size_t)ar1) << 10) + kc16s;
  const u16* sB2 = wdh + ((bcol + 64 + (size_t)ar1) << 10) + kc16s;
  int aoff[4], boff[4];
  #pragma unroll
  for (int mi = 0; mi < 4; ++mi) aoff[mi] = roff(wm*64 + mi*16 + lr, lks);
  #pragma unroll
  for (int ni = 0; ni < 4; ++ni) boff[ni] = roff(wn*64 + ni*16 + lr, lks);
  f32x4 hh[4][4];
  #pragma unroll
  for (int i = 0; i < 4; ++i)
    #pragma unroll
    for (int j = 0; j < 4; ++j)
      #pragma unroll
      for (int r = 0; r < 4; ++r) hh[i][j][r] = 0.f;
#define STG_DH(buf, kc) do{ \
    gl_lds16(sAh1 + (kc), &Ah[buf][t*8]); \
    gl_lds16(sAh2 + (kc), &Ah[buf][2048 + t*8]); \
    gl_lds16(sB1 + (kc), &Bh[buf][t*8]); \
    gl_lds16(sB2 + (kc), &Bh[buf][2048 + t*8]); }while(0)
  STG_DH(0, 0);
  for (int ks = 0; ks < 32; ++ks){
    int cur = ks & 1;
    __syncthreads();
    if (ks < 31) STG_DH(cur^1, (ks+1)*32);
    f16x8 ah[4], bh[4];
    #pragma unroll
    for (int mi = 0; mi < 4; ++mi) ah[mi] = *(const f16x8*)&Ah[cur][aoff[mi]];
    #pragma unroll
    for (int ni = 0; ni < 4; ++ni) bh[ni] = *(const f16x8*)&Bh[cur][boff[ni]];
    #pragma unroll
    for (int mi = 0; mi < 4; ++mi)
      #pragma unroll
      for (int ni = 0; ni < 4; ++ni)
        hh[mi][ni] = __builtin_amdgcn_mfma_f32_16x16x32_f16(ah[mi], bh[ni], hh[mi][ni], 0, 0, 0);
  }
#undef STG_DH
  #pragma unroll
  for (int mi = 0; mi < 4; ++mi){
    int rb = row0 + wm*64 + mi*16 + lks*4;
    #pragma unroll
    for (int r = 0; r < 4; ++r){
      int rr = rb + r;
      if (rr < cnt){
        float* orow = eo + (((size_t)(base + rr)) << 9) + nt*128;
        #pragma unroll
        for (int ni = 0; ni < 4; ++ni)
          orow[wn*64 + ni*16 + lr] = hh[mi][ni][r];
      }
    }
  }
}

// ---------------- gather + residual (final layer) ----------------
__global__ __launch_bounds__(128) void gather_kernel(const float* __restrict__ xin,
    const float* __restrict__ eo, const int* __restrict__ slot_of, const float* __restrict__ wv,
    float* __restrict__ out){
  int n = blockIdx.x, t = threadIdx.x;
  int s0 = slot_of[2*n], s1 = slot_of[2*n+1];
  double w0 = wv[2*n], w1 = wv[2*n+1];
  float4 xi = *(const float4*)&xin[((size_t)n << 9) + t*4];
  float4 e0 = *(const float4*)&eo[((size_t)s0 << 9) + t*4];
  float4 e1 = *(const float4*)&eo[((size_t)s1 << 9) + t*4];
  float4 o;
  o.x = (float)((double)xi.x + w0*(double)e0.x + w1*(double)e1.x);
  o.y = (float)((double)xi.y + w0*(double)e0.y + w1*(double)e1.y);
  o.z = (float)((double)xi.z + w0*(double)e0.z + w1*(double)e1.z);
  o.w = (float)((double)xi.w + w0*(double)e0.w + w1*(double)e1.w);
  *(float4*)&out[((size_t)n << 9) + t*4] = o;
}

extern "C" void kernel_launch(void* const* d_in, const int* in_sizes, int n_in,
                              void* d_out, int out_size, void* d_ws, size_t ws_size,
                              hipStream_t stream) {
  (void)in_sizes; (void)n_in; (void)out_size; (void)ws_size;
  const float* x0   = (const float*)d_in[0];
  const int*   sid  = (const int*)  d_in[1];
  const float* ln_g = (const float*)d_in[2];
  const float* ln_b = (const float*)d_in[3];
  const float* semb = (const float*)d_in[4];
  const float* h1w  = (const float*)d_in[5];
  const float* h1b  = (const float*)d_in[6];
  const float* h2w  = (const float*)d_in[7];
  const float* h2b  = (const float*)d_in[8];
  const float* s1w  = (const float*)d_in[9];
  const float* s1b  = (const float*)d_in[10];
  const float* s2w  = (const float*)d_in[11];
  const float* s2b  = (const float*)d_in[12];
  const float* g1w  = (const float*)d_in[13];
  const float* g1b  = (const float*)d_in[14];
  const float* g2w  = (const float*)d_in[15];
  const float* g2b  = (const float*)d_in[16];
  const float* wi0  = (const float*)d_in[17];
  const float* wi1  = (const float*)d_in[18];
  const float* wo   = (const float*)d_in[19];

  char* W = (char*)d_ws;
  float*  h      = (float*)(W + 0);                  // 16 MB
  u16*    hfh    = (u16*)  (W + 16777216ULL);        // 8 MB
  u16*    hfl    = (u16*)  (W + 25165824ULL);        // 8 MB
  float*  eo32   = (float*)(W + 167772160ULL);       // 32 MB
  u16*    hid16h = (u16*)  (W + 33554432ULL);        // 32 MB
  u16*    hid16l = (u16*)  (W + 67108864ULL);        // 32 MB
  u16*    w0Th   = (u16*)  (W + 100663296ULL);       // 8 MB each
  u16*    w0Tl   = (u16*)  (W + 109051904ULL);
  u16*    w1Th   = (u16*)  (W + 117440512ULL);
  u16*    w1Tl   = (u16*)  (W + 125829120ULL);
  u16*    woTh   = (u16*)  (W + 134217728ULL);
  u16*    woTl   = (u16*)  (W + 142606336ULL);
  u16*    g1Th   = (u16*)  (W + 150994944ULL);
  u16*    g1Tl   = (u16*)  (W + 151257088ULL);
  double* a64    = (double*)(W + 151584768ULL);
  double* c64    = (double*)(W + 151617536ULL);
  int*    idxa   = (int*)   (W + 151650304ULL);
  float*  warr   = (float*) (W + 151715840ULL);
  int*    tok_of = (int*)   (W + 151781376ULL);
  int*    slot_of= (int*)   (W + 151846912ULL);
  int*    counts = (int*)   (W + 151912448ULL);
  int*    cur    = counts + 8;
  int*    offs   = counts + 16;
  double* partS  = (double*)(W + 152043520ULL);      // 256 KB
  double* partQ  = (double*)(W + 152305664ULL);      // 256 KB

  cvt_all<<<12416, 256, 0, stream>>>(wi0, wi1, wo, g1w,
                                     w0Th, w0Tl, w1Th, w1Tl, woTh, woTl, g1Th, g1Tl);

  // ---- layer 0 ----
  ln_kernel<<<8192, 256, 0, stream>>>(x0, ln_g, ln_b, h);
  colstats<<<512, 256, 0, stream>>>(h, partS, partQ);
  subj_kernel<<<8, 256, 0, stream>>>(sid, semb, h1w, h1b, h2w, h2b, s1w, s1b, s2w, s2b,
                                     partS, partQ, a64, c64, 0);
  hfcast<<<2048, 256, 0, stream>>>(h, a64, c64, hfh, hfl, counts);
  gate2_kernel<<<512, 256, 0, stream>>>(hfh, hfl, g1Th, g1Tl, g1b, g2w, g2b, idxa, warr, counts);
  scatter_kernel<<<32, 256, 0, stream>>>(idxa, counts, cur, offs, tok_of, slot_of);
  up1_kernel<<<16384, 256, 0, stream>>>(hfh, hfl, w0Th, w0Tl, w1Th, w1Tl,
                                        tok_of, offs, counts, hid16h, hid16l);
  down1_kernel<<<8192, 256, 0, stream>>>(hid16h, hid16l, woTh, woTl, offs, counts, eo32);
  gather_ln<<<8192, 128, 0, stream>>>(x0, eo32, slot_of, warr, ln_g + 512, ln_b + 512,
                                      (float*)d_out, h);
  // ---- layer 1 ----
  colstats<<<512, 256, 0, stream>>>(h, partS, partQ);
  subj_kernel<<<8, 256, 0, stream>>>(sid, semb, h1w, h1b, h2w, h2b, s1w, s1b, s2w, s2b,
                                     partS, partQ, a64, c64, 1);
  hfcast<<<2048, 256, 0, stream>>>(h, a64, c64, hfh, hfl, counts);
  gate2_kernel<<<512, 256, 0, stream>>>(hfh, hfl, g1Th, g1Tl, g1b, g2w, g2b, idxa, warr, counts);
  scatter_kernel<<<32, 256, 0, stream>>>(idxa, counts, cur, offs, tok_of, slot_of);
  uph_kernel<<<8192, 256, 0, stream>>>(hfh, w0Th, w1Th, tok_of, offs, counts, hid16h);
  dnh_kernel<<<4096, 256, 0, stream>>>(hid16h, woTh, offs, counts, eo32);
  gather_kernel<<<8192, 128, 0, stream>>>((const float*)d_out, eo32, slot_of, warr, (float*)d_out);
}